// Round 2
// baseline (487.669 us; speedup 1.0000x reference)
//
#include <hip/hip_runtime.h>
#include <hip/hip_bf16.h>

typedef __attribute__((ext_vector_type(8))) short s8v;   // 8 x bf16 (bit pattern)
typedef __attribute__((ext_vector_type(4))) float f4v;   // MFMA accumulator

#define DEV static __device__ __forceinline__

DEV unsigned short f2bf(float f) {
    unsigned int u = __builtin_bit_cast(unsigned int, f);
    unsigned int r = u + 0x7FFFu + ((u >> 16) & 1u);
    return (unsigned short)(r >> 16);
}

DEV f4v fzero() { f4v v = {0.f, 0.f, 0.f, 0.f}; return v; }

DEV void gload16(const void* g, void* l) {
    __builtin_amdgcn_global_load_lds(
        (const __attribute__((address_space(1))) unsigned int*)g,
        (__attribute__((address_space(3))) unsigned int*)l, 16, 0, 0);
}

// ---------------- weight transpose f32 (K,N) -> bf16 (N,K) ----------------
__global__ __launch_bounds__(256) void k_transpose_bf16(
        const float* __restrict__ W, unsigned short* __restrict__ Wt, int K, int N) {
    __shared__ float tile[32][33];
    int tx = threadIdx.x & 31, ty = threadIdx.x >> 5;
    int n0 = blockIdx.x * 32, k0 = blockIdx.y * 32;
#pragma unroll
    for (int r = 0; r < 32; r += 8)
        tile[ty + r][tx] = W[(size_t)(k0 + ty + r) * N + n0 + tx];
    __syncthreads();
#pragma unroll
    for (int r = 0; r < 32; r += 8)
        Wt[(size_t)(n0 + ty + r) * K + k0 + tx] = f2bf(tile[tx][ty + r]);
}

// ---------------- elementwise f32 -> bf16 ----------------
__global__ __launch_bounds__(256) void k_f32_to_bf16(
        const float* __restrict__ in, unsigned short* __restrict__ out, int n) {
    int i = (blockIdx.x * 256 + threadIdx.x) * 8;
    if (i >= n) return;
    float4 a = *(const float4*)(in + i);
    float4 b = *(const float4*)(in + i + 4);
    uint4 o;
    o.x = f2bf(a.x) | ((unsigned)f2bf(a.y) << 16);
    o.y = f2bf(a.z) | ((unsigned)f2bf(a.w) << 16);
    o.z = f2bf(b.x) | ((unsigned)f2bf(b.y) << 16);
    o.w = f2bf(b.z) | ((unsigned)f2bf(b.w) << 16);
    *(uint4*)(out + i) = o;
}

// ---------------- bias concat: [sa_bq|sa_bk|sa_bv|ca_bk|ca_bv] ----------------
__global__ __launch_bounds__(256) void k_bias_cat(
        const float* q, const float* k, const float* v,
        const float* k2, const float* v2, float* out) {
    int i = blockIdx.x * 256 + threadIdx.x;  // 5120 total
    float val;
    if (i < 1024) val = q[i];
    else if (i < 2048) val = k[i - 1024];
    else if (i < 3072) val = v[i - 2048];
    else if (i < 4096) val = k2[i - 3072];
    else val = v2[i - 4096];
    out[i] = val;
}

// ---------------- LayerNorm f32 -> bf16 (C=1024) ----------------
__global__ __launch_bounds__(256) void k_layernorm(
        const float* __restrict__ x, const float* __restrict__ g,
        const float* __restrict__ b, unsigned short* __restrict__ out) {
    int row = blockIdx.x;
    int t = threadIdx.x;
    const float* xr = x + (size_t)row * 1024;
    float4 v = *(const float4*)(xr + t * 4);
    float s = v.x + v.y + v.z + v.w;
    float ss = v.x * v.x + v.y * v.y + v.z * v.z + v.w * v.w;
#pragma unroll
    for (int m = 1; m < 64; m <<= 1) { s += __shfl_xor(s, m); ss += __shfl_xor(ss, m); }
    __shared__ float red[16];
    int w = t >> 6;
    if ((t & 63) == 0) { red[w] = s; red[8 + w] = ss; }
    __syncthreads();
    s = red[0] + red[1] + red[2] + red[3];
    ss = red[8] + red[9] + red[10] + red[11];
    float mu = s * (1.f / 1024.f);
    float rstd = rsqrtf(ss * (1.f / 1024.f) - mu * mu + 1e-5f);
    float4 gv = *(const float4*)(g + t * 4);
    float4 bv = *(const float4*)(b + t * 4);
    float y0 = (v.x - mu) * rstd * gv.x + bv.x;
    float y1 = (v.y - mu) * rstd * gv.y + bv.y;
    float y2 = (v.z - mu) * rstd * gv.z + bv.z;
    float y3 = (v.w - mu) * rstd * gv.w + bv.w;
    uint2 o;
    o.x = f2bf(y0) | ((unsigned)f2bf(y1) << 16);
    o.y = f2bf(y2) | ((unsigned)f2bf(y3) << 16);
    *(uint2*)(out + (size_t)row * 1024 + t * 4) = o;
}

// ---------------- GEMM: A(M,K)bf16 @ Bt(N,K)bf16 + bias, m97 128^2 structure ----
// EPI 0: out bf16   1: out bf16 gelu(exact)   2: out f32 = res + acc + bias
template <int EPI>
__global__ __launch_bounds__(256) void k_gemm(
        const unsigned short* __restrict__ A, const unsigned short* __restrict__ Bt,
        const float* __restrict__ bias, const float* __restrict__ res,
        void* __restrict__ outv, int M, int N, int K) {
    __shared__ unsigned short As[128 * 32];
    __shared__ unsigned short Bs[128 * 32];
    int nbx = N >> 7;
    int bx = blockIdx.x % nbx, by = blockIdx.x / nbx;
    int m0 = by << 7, n0 = bx << 7;
    int tid = threadIdx.x, w = tid >> 6, l = tid & 63;
    int wr = w >> 1, wc = w & 1;
    int lq = l >> 4, lc = l & 15;
    f4v acc[4][4];
#pragma unroll
    for (int i = 0; i < 4; ++i)
#pragma unroll
        for (int j = 0; j < 4; ++j) acc[i][j] = fzero();
    const unsigned short* Ab = A + (size_t)m0 * K;
    const unsigned short* Bb = Bt + (size_t)n0 * K;
    int arow = w * 16 + (l >> 2);
    int ach = (l & 3) * 8;
    for (int kt = 0; kt < K; kt += 32) {
#pragma unroll
        for (int s = 0; s < 2; ++s) {
            gload16(Ab + (size_t)(s * 64 + arow) * K + kt + ach, (char*)As + s * 4096 + w * 1024);
            gload16(Bb + (size_t)(s * 64 + arow) * K + kt + ach, (char*)Bs + s * 4096 + w * 1024);
        }
        __syncthreads();
        s8v af[4], bfr[4];
#pragma unroll
        for (int i = 0; i < 4; ++i) {
            af[i]  = *(const s8v*)((const char*)As + (wr * 64 + i * 16 + lc) * 64 + lq * 16);
            bfr[i] = *(const s8v*)((const char*)Bs + (wc * 64 + i * 16 + lc) * 64 + lq * 16);
        }
#pragma unroll
        for (int i = 0; i < 4; ++i)
#pragma unroll
            for (int j = 0; j < 4; ++j)
                acc[i][j] = __builtin_amdgcn_mfma_f32_16x16x32_bf16(af[i], bfr[j], acc[i][j], 0, 0, 0);
        __syncthreads();
    }
#pragma unroll
    for (int j = 0; j < 4; ++j) {
        int col = n0 + wc * 64 + j * 16 + lc;
        float bv = bias[col];
#pragma unroll
        for (int i = 0; i < 4; ++i) {
            int rbase = m0 + wr * 64 + i * 16 + lq * 4;
#pragma unroll
            for (int r = 0; r < 4; ++r) {
                float vacc = acc[i][j][r] + bv;
                size_t idx = (size_t)(rbase + r) * N + col;
                if (EPI == 0) {
                    ((unsigned short*)outv)[idx] = f2bf(vacc);
                } else if (EPI == 1) {
                    float ge = 0.5f * vacc * (1.0f + erff(vacc * 0.70710678118f));
                    ((unsigned short*)outv)[idx] = f2bf(ge);
                } else {
                    ((float*)outv)[idx] = res[idx] + vacc;
                }
            }
        }
    }
}

// ---------------- fused flash attention (d=64, 64x64 tiles, 4 waves) ----------
__global__ __launch_bounds__(256) void k_attn(
        const unsigned short* __restrict__ Q, int ldq,
        const unsigned short* __restrict__ Kp, int ldk,
        const unsigned short* __restrict__ Vp, int ldv,
        unsigned short* __restrict__ O, int ldo,
        int T, int causal) {
    __shared__ unsigned short Ks[64 * 64];     // [t][d], chunk-swizzled
    __shared__ unsigned short Vt[64 * 64];     // [d][t], chunk-swizzled
    __shared__ unsigned short Ps[4][16 * 64];  // per-wave P, chunk-swizzled
    int nqt = T >> 6;
    int qt = blockIdx.x % nqt;
    int bh = blockIdx.x / nqt;
    int b = bh >> 4, h = bh & 15;
    int tid = threadIdx.x, w = tid >> 6, l = tid & 63;
    int lq = l >> 4, lc = l & 15;
    size_t qoff = (size_t)b * T * ldq + h * 64;
    size_t koff = (size_t)b * T * ldk + h * 64;
    size_t voff = (size_t)b * T * ldv + h * 64;
    s8v qf[2];
    {
        const unsigned short* qp = Q + qoff + (size_t)(qt * 64 + w * 16 + lc) * ldq + lq * 8;
        qf[0] = *(const s8v*)qp;
        qf[1] = *(const s8v*)(qp + 32);
    }
    f4v o_acc[4];
#pragma unroll
    for (int j = 0; j < 4; ++j) o_acc[j] = fzero();
    float mrow[4], lrow[4];
#pragma unroll
    for (int j = 0; j < 4; ++j) { mrow[j] = -3.0e38f; lrow[j] = 0.f; }
    int p = tid & 31, dbase = (tid >> 5) * 8;
    int ktend = causal ? (qt + 1) : (T >> 6);
    for (int kt = 0; kt < ktend; ++kt) {
        // ---- stage K via global_load_lds, source pre-swizzled (m173 pattern)
#pragma unroll
        for (int s = 0; s < 2; ++s) {
            int idx = s * 256 + w * 64 + l;
            int t = idx >> 3;
            int ch = (idx & 7) ^ (t & 7);
            gload16(Kp + koff + (size_t)(kt * 64 + t) * ldk + ch * 8,
                    (char*)Ks + s * 4096 + w * 1024);
        }
        // ---- stage V transposed + swizzled (2 rows packed per u32 write)
        {
            const unsigned short* vp = Vp + voff + (size_t)(kt * 64 + 2 * p) * ldv + dbase;
            s8v v0 = *(const s8v*)vp;
            s8v v1 = *(const s8v*)(vp + ldv);
#pragma unroll
            for (int j = 0; j < 8; ++j) {
                int dd = dbase + j;
                unsigned int val = (unsigned short)v0[j] | ((unsigned)(unsigned short)v1[j] << 16);
                *(unsigned int*)((char*)Vt + dd * 128 +
                                 ((((p >> 2) ^ (dd & 7)) << 4) | ((p & 3) << 2))) = val;
            }
        }
        __syncthreads();
        // ---- S = Q K^T (16 q-rows per wave x 64 k-cols)
        f4v sa[4];
#pragma unroll
        for (int jn = 0; jn < 4; ++jn) {
            sa[jn] = fzero();
            int t = jn * 16 + lc;
#pragma unroll
            for (int kc = 0; kc < 2; ++kc) {
                s8v bf = *(const s8v*)((const char*)Ks + t * 128 +
                                       (((kc * 4 + lq) ^ (t & 7)) << 4));
                sa[jn] = __builtin_amdgcn_mfma_f32_16x16x32_bf16(qf[kc], bf, sa[jn], 0, 0, 0);
            }
        }
        // ---- online softmax (per reg-row j)
        bool diag = (causal && kt == qt);
#pragma unroll
        for (int j = 0; j < 4; ++j) {
            float pv[4];
            float tm = -3.0e38f;
#pragma unroll
            for (int jn = 0; jn < 4; ++jn) {
                float sv = sa[jn][j] * 0.125f;
                if (diag) {
                    int qg = w * 16 + lq * 4 + j;
                    int kg = jn * 16 + lc;
                    if (kg > qg) sv = -3.0e38f;
                }
                pv[jn] = sv;
                tm = fmaxf(tm, sv);
            }
#pragma unroll
            for (int m = 1; m < 16; m <<= 1) tm = fmaxf(tm, __shfl_xor(tm, m));
            float mnew = fmaxf(mrow[j], tm);
            float alpha = __expf(mrow[j] - mnew);
            mrow[j] = mnew;
            float rs = 0.f;
#pragma unroll
            for (int jn = 0; jn < 4; ++jn) {
                float e = __expf(pv[jn] - mnew);
                rs += e;
                int colx = jn * 16 + lc;
                int rowx = lq * 4 + j;
                *(unsigned short*)((char*)Ps[w] + rowx * 128 +
                                   ((((colx >> 3) ^ (rowx & 7)) << 4) | ((colx & 7) << 1))) = f2bf(e);
            }
#pragma unroll
            for (int m = 1; m < 16; m <<= 1) rs += __shfl_xor(rs, m);
            lrow[j] = lrow[j] * alpha + rs;
#pragma unroll
            for (int jn = 0; jn < 4; ++jn) o_acc[jn][j] *= alpha;
        }
        // ---- O += P V (wave-private Ps, no barrier needed before reads)
#pragma unroll
        for (int kc = 0; kc < 2; ++kc) {
            s8v af = *(const s8v*)((const char*)Ps[w] + lc * 128 +
                                   (((kc * 4 + lq) ^ (lc & 7)) << 4));
#pragma unroll
            for (int jn = 0; jn < 4; ++jn) {
                int dd = jn * 16 + lc;
                s8v bf = *(const s8v*)((const char*)Vt + dd * 128 +
                                       (((kc * 4 + lq) ^ (dd & 7)) << 4));
                o_acc[jn] = __builtin_amdgcn_mfma_f32_16x16x32_bf16(af, bf, o_acc[jn], 0, 0, 0);
            }
        }
        __syncthreads();
    }
#pragma unroll
    for (int j = 0; j < 4; ++j) {
        float inv = 1.0f / lrow[j];
        int row = qt * 64 + w * 16 + lq * 4 + j;
#pragma unroll
        for (int jn = 0; jn < 4; ++jn)
            O[(size_t)(b * T + row) * ldo + h * 64 + jn * 16 + lc] = f2bf(o_acc[jn][j] * inv);
    }
}

// ---------------- orchestration ----------------
extern "C" void kernel_launch(void* const* d_in, const int* in_sizes, int n_in,
                              void* d_out, int out_size, void* d_ws, size_t ws_size,
                              hipStream_t stream) {
    const float* x     = (const float*)d_in[0];
    const float* ctx   = (const float*)d_in[1];
    const float* ln1_g = (const float*)d_in[2];
    const float* ln1_b = (const float*)d_in[3];
    const float* ln2_g = (const float*)d_in[4];
    const float* ln2_b = (const float*)d_in[5];
    const float* sa_wq = (const float*)d_in[6];  const float* sa_bq = (const float*)d_in[7];
    const float* sa_wk = (const float*)d_in[8];  const float* sa_bk = (const float*)d_in[9];
    const float* sa_wv = (const float*)d_in[10]; const float* sa_bv = (const float*)d_in[11];
    const float* sa_wo = (const float*)d_in[12]; const float* sa_bo = (const float*)d_in[13];
    const float* ca_wq = (const float*)d_in[14]; const float* ca_bq = (const float*)d_in[15];
    const float* ca_wk = (const float*)d_in[16]; const float* ca_bk = (const float*)d_in[17];
    const float* ca_wv = (const float*)d_in[18]; const float* ca_bv = (const float*)d_in[19];
    const float* ca_wo = (const float*)d_in[20]; const float* ca_bo = (const float*)d_in[21];
    const float* w1 = (const float*)d_in[22]; const float* b1 = (const float*)d_in[23];
    const float* w2 = (const float*)d_in[24]; const float* b2 = (const float*)d_in[25];
    float* out = (float*)d_out;

    char* ws = (char*)d_ws;
    const size_t MB = 1024 * 1024;
    unsigned short* wt_saq = (unsigned short*)(ws + 0 * MB);   // 2MB each; saq,sak,sav contiguous
    unsigned short* wt_sak = (unsigned short*)(ws + 2 * MB);
    unsigned short* wt_sav = (unsigned short*)(ws + 4 * MB);
    unsigned short* wt_sao = (unsigned short*)(ws + 6 * MB);
    unsigned short* wt_caq = (unsigned short*)(ws + 8 * MB);
    unsigned short* wt_cak = (unsigned short*)(ws + 10 * MB);  // cak,cav contiguous
    unsigned short* wt_cav = (unsigned short*)(ws + 12 * MB);
    unsigned short* wt_cao = (unsigned short*)(ws + 14 * MB);
    unsigned short* w1t    = (unsigned short*)(ws + 16 * MB);  // 8MB (4096,1024)
    unsigned short* w2t    = (unsigned short*)(ws + 24 * MB);  // 8MB (1024,4096)
    unsigned short* ctxb   = (unsigned short*)(ws + 32 * MB);  // 8MB; reused as h3 in MLP
    float*          x1     = (float*)        (ws + 40 * MB);   // 16MB
    unsigned short* qbuf   = (unsigned short*)(ws + 56 * MB);  // 8MB, start of qkv region
    unsigned short* kbuf   = (unsigned short*)(ws + 64 * MB);  // 8MB, kv region
    unsigned short* hln    = (unsigned short*)(ws + 80 * MB);  // 8MB (ln out / attn out)
    float*          bcat   = (float*)        (ws + 88 * MB);   // 20KB
    unsigned short* qkv = qbuf;   // (4096,3072) spans 56..80MB
    unsigned short* kv  = kbuf;   // (4096,2048) spans 64..80MB
    unsigned short* m1  = qbuf;   // (4096,4096) = 32MB spans 56..88MB
    unsigned short* h3  = ctxb;

    dim3 blk(256);
    // weight prep
    k_transpose_bf16<<<dim3(32, 32), blk, 0, stream>>>(sa_wq, wt_saq, 1024, 1024);
    k_transpose_bf16<<<dim3(32, 32), blk, 0, stream>>>(sa_wk, wt_sak, 1024, 1024);
    k_transpose_bf16<<<dim3(32, 32), blk, 0, stream>>>(sa_wv, wt_sav, 1024, 1024);
    k_transpose_bf16<<<dim3(32, 32), blk, 0, stream>>>(sa_wo, wt_sao, 1024, 1024);
    k_transpose_bf16<<<dim3(32, 32), blk, 0, stream>>>(ca_wq, wt_caq, 1024, 1024);
    k_transpose_bf16<<<dim3(32, 32), blk, 0, stream>>>(ca_wk, wt_cak, 1024, 1024);
    k_transpose_bf16<<<dim3(32, 32), blk, 0, stream>>>(ca_wv, wt_cav, 1024, 1024);
    k_transpose_bf16<<<dim3(32, 32), blk, 0, stream>>>(ca_wo, wt_cao, 1024, 1024);
    k_transpose_bf16<<<dim3(128, 32), blk, 0, stream>>>(w1, w1t, 1024, 4096);
    k_transpose_bf16<<<dim3(32, 128), blk, 0, stream>>>(w2, w2t, 4096, 1024);
    k_f32_to_bf16<<<dim3(2048), blk, 0, stream>>>(ctx, ctxb, 4 * 1024 * 1024);
    k_bias_cat<<<dim3(20), blk, 0, stream>>>(sa_bq, sa_bk, sa_bv, ca_bk, ca_bv, bcat);

    // ---- self attention: x1 = x + Wo(attn(ln1(x))) ----
    k_layernorm<<<dim3(4096), blk, 0, stream>>>(x, ln1_g, ln1_b, hln);
    k_gemm<0><<<dim3(24 * 32), blk, 0, stream>>>(hln, wt_saq, bcat, nullptr, qkv, 4096, 3072, 1024);
    k_attn<<<dim3(1024), blk, 0, stream>>>(qkv, 3072, qkv + 1024, 3072, qkv + 2048, 3072,
                                           hln, 1024, 1024, 1);
    k_gemm<2><<<dim3(8 * 32), blk, 0, stream>>>(hln, wt_sao, sa_bo, x, x1, 4096, 1024, 1024);

    // ---- cross attention: x2 = x1 + Wo(attn(ln2(x1), ctx)) ----
    k_layernorm<<<dim3(4096), blk, 0, stream>>>(x1, ln2_g, ln2_b, hln);
    k_gemm<0><<<dim3(8 * 32), blk, 0, stream>>>(hln, wt_caq, ca_bq, nullptr, qbuf, 4096, 1024, 1024);
    k_gemm<0><<<dim3(16 * 32), blk, 0, stream>>>(ctxb, wt_cak, bcat + 3072, nullptr, kv, 4096, 2048, 1024);
    k_attn<<<dim3(1024), blk, 0, stream>>>(qbuf, 1024, kv, 2048, kv + 1024, 2048,
                                           hln, 1024, 1024, 0);
    k_gemm<2><<<dim3(8 * 32), blk, 0, stream>>>(hln, wt_cao, ca_bo, x1, out, 4096, 1024, 1024);

    // ---- MLP: out = x2 + W2(gelu(W1(ln2(x2)))) ----
    k_layernorm<<<dim3(4096), blk, 0, stream>>>(out, ln2_g, ln2_b, h3);
    k_gemm<1><<<dim3(32 * 32), blk, 0, stream>>>(h3, w1t, b1, nullptr, m1, 4096, 4096, 1024);
    k_gemm<2><<<dim3(8 * 32), blk, 0, stream>>>(m1, w2t, b2, out, out, 4096, 1024, 4096);
}

// Round 3
// 419.420 us; speedup vs baseline: 1.1627x; 1.1627x over previous
//
#include <hip/hip_runtime.h>
#include <hip/hip_bf16.h>

typedef __attribute__((ext_vector_type(8))) short s8v;   // 8 x bf16 (bit pattern)
typedef __attribute__((ext_vector_type(4))) float f4v;   // MFMA accumulator

#define DEV static __device__ __forceinline__

DEV unsigned short f2bf(float f) {
    unsigned int u = __builtin_bit_cast(unsigned int, f);
    unsigned int r = u + 0x7FFFu + ((u >> 16) & 1u);
    return (unsigned short)(r >> 16);
}

DEV f4v fzero() { f4v v = {0.f, 0.f, 0.f, 0.f}; return v; }

DEV void gload16(const void* g, void* l) {
    __builtin_amdgcn_global_load_lds(
        (const __attribute__((address_space(1))) unsigned int*)g,
        (__attribute__((address_space(3))) unsigned int*)l, 16, 0, 0);
}

// ---------------- weight transpose f32 (K,N) -> bf16 (N,K) ----------------
__global__ __launch_bounds__(256) void k_transpose_bf16(
        const float* __restrict__ W, unsigned short* __restrict__ Wt, int K, int N) {
    __shared__ float tile[32][33];
    int tx = threadIdx.x & 31, ty = threadIdx.x >> 5;
    int n0 = blockIdx.x * 32, k0 = blockIdx.y * 32;
#pragma unroll
    for (int r = 0; r < 32; r += 8)
        tile[ty + r][tx] = W[(size_t)(k0 + ty + r) * N + n0 + tx];
    __syncthreads();
#pragma unroll
    for (int r = 0; r < 32; r += 8)
        Wt[(size_t)(n0 + ty + r) * K + k0 + tx] = f2bf(tile[tx][ty + r]);
}

// ---------------- elementwise f32 -> bf16 ----------------
__global__ __launch_bounds__(256) void k_f32_to_bf16(
        const float* __restrict__ in, unsigned short* __restrict__ out, int n) {
    int i = (blockIdx.x * 256 + threadIdx.x) * 8;
    if (i >= n) return;
    float4 a = *(const float4*)(in + i);
    float4 b = *(const float4*)(in + i + 4);
    uint4 o;
    o.x = f2bf(a.x) | ((unsigned)f2bf(a.y) << 16);
    o.y = f2bf(a.z) | ((unsigned)f2bf(a.w) << 16);
    o.z = f2bf(b.x) | ((unsigned)f2bf(b.y) << 16);
    o.w = f2bf(b.z) | ((unsigned)f2bf(b.w) << 16);
    *(uint4*)(out + i) = o;
}

// ---------------- bias concat: [sa_bq|sa_bk|sa_bv|ca_bk|ca_bv] ----------------
__global__ __launch_bounds__(256) void k_bias_cat(
        const float* q, const float* k, const float* v,
        const float* k2, const float* v2, float* out) {
    int i = blockIdx.x * 256 + threadIdx.x;  // 5120 total
    float val;
    if (i < 1024) val = q[i];
    else if (i < 2048) val = k[i - 1024];
    else if (i < 3072) val = v[i - 2048];
    else if (i < 4096) val = k2[i - 3072];
    else val = v2[i - 4096];
    out[i] = val;
}

// ---------------- LayerNorm f32 -> bf16 (C=1024) ----------------
__global__ __launch_bounds__(256) void k_layernorm(
        const float* __restrict__ x, const float* __restrict__ g,
        const float* __restrict__ b, unsigned short* __restrict__ out) {
    int row = blockIdx.x;
    int t = threadIdx.x;
    const float* xr = x + (size_t)row * 1024;
    float4 v = *(const float4*)(xr + t * 4);
    float s = v.x + v.y + v.z + v.w;
    float ss = v.x * v.x + v.y * v.y + v.z * v.z + v.w * v.w;
#pragma unroll
    for (int m = 1; m < 64; m <<= 1) { s += __shfl_xor(s, m); ss += __shfl_xor(ss, m); }
    __shared__ float red[16];
    int w = t >> 6;
    if ((t & 63) == 0) { red[w] = s; red[8 + w] = ss; }
    __syncthreads();
    s = red[0] + red[1] + red[2] + red[3];
    ss = red[8] + red[9] + red[10] + red[11];
    float mu = s * (1.f / 1024.f);
    float rstd = rsqrtf(ss * (1.f / 1024.f) - mu * mu + 1e-5f);
    float4 gv = *(const float4*)(g + t * 4);
    float4 bv = *(const float4*)(b + t * 4);
    float y0 = (v.x - mu) * rstd * gv.x + bv.x;
    float y1 = (v.y - mu) * rstd * gv.y + bv.y;
    float y2 = (v.z - mu) * rstd * gv.z + bv.z;
    float y3 = (v.w - mu) * rstd * gv.w + bv.w;
    uint2 o;
    o.x = f2bf(y0) | ((unsigned)f2bf(y1) << 16);
    o.y = f2bf(y2) | ((unsigned)f2bf(y3) << 16);
    *(uint2*)(out + (size_t)row * 1024 + t * 4) = o;
}

// ---------------- GEMM: A(M,K)bf16 @ Bt(N,K)bf16 + bias -------------------
// 2-phase double-buffered prefetch (T3-minimum), XCD-bijective swizzle (T1),
// LDS-bounce coalesced epilogue. BN=128 fixed; BM in {128, 64}.
// EPI 0: out bf16   1: out bf16 gelu(exact)   2: out f32 = res + acc + bias
template <int EPI, int BM>
__global__ __launch_bounds__(256) void k_gemm(
        const unsigned short* __restrict__ A, const unsigned short* __restrict__ Bt,
        const float* __restrict__ bias, const float* __restrict__ res,
        void* __restrict__ outv, int M, int N, int K) {
    constexpr int WI = (BM == 128) ? 4 : 2;       // 16-row frags per wave
    constexpr int ABUF = BM * 64;                 // bytes per A staging buffer
    __shared__ __align__(16) char smem[BM * 128 + 16384];
    char* Asm = smem;                  // 2 bufs x ABUF
    char* Bsm = smem + 2 * ABUF;       // 2 bufs x 8192
    int nbx = N >> 7;
    int bid = blockIdx.x;
    int cpx = gridDim.x >> 3;          // all grids are %8 == 0
    int swz = (bid & 7) * cpx + (bid >> 3);
    int bx = swz % nbx, by = swz / nbx;
    int m0 = by * BM, n0 = bx << 7;
    int tid = threadIdx.x, w = tid >> 6, l = tid & 63;
    int wr = w >> 1, wc = w & 1;
    int lq = l >> 4, lc = l & 15;
    f4v acc[WI][4];
#pragma unroll
    for (int i = 0; i < WI; ++i)
#pragma unroll
        for (int j = 0; j < 4; ++j) acc[i][j] = fzero();
    const unsigned short* Ab = A + (size_t)m0 * K;
    const unsigned short* Bb = Bt + (size_t)n0 * K;
    int arow = w * 16 + (l >> 2);      // 0..63
    int ach = (l & 3) * 8;

    auto STAGE = [&](int kt, int buf) {
        gload16(Ab + (size_t)arow * K + kt + ach, Asm + buf * ABUF + w * 1024);
        if constexpr (BM == 128)
            gload16(Ab + (size_t)(64 + arow) * K + kt + ach, Asm + buf * ABUF + 4096 + w * 1024);
        gload16(Bb + (size_t)arow * K + kt + ach, Bsm + buf * 8192 + w * 1024);
        gload16(Bb + (size_t)(64 + arow) * K + kt + ach, Bsm + buf * 8192 + 4096 + w * 1024);
    };
    auto COMPUTE = [&](int buf) {
        s8v af[WI], bfr[4];
#pragma unroll
        for (int i = 0; i < WI; ++i)
            af[i] = *(const s8v*)(Asm + buf * ABUF + (wr * (BM / 2) + i * 16 + lc) * 64 + lq * 16);
#pragma unroll
        for (int j = 0; j < 4; ++j)
            bfr[j] = *(const s8v*)(Bsm + buf * 8192 + (wc * 64 + j * 16 + lc) * 64 + lq * 16);
#pragma unroll
        for (int i = 0; i < WI; ++i)
#pragma unroll
            for (int j = 0; j < 4; ++j)
                acc[i][j] = __builtin_amdgcn_mfma_f32_16x16x32_bf16(af[i], bfr[j], acc[i][j], 0, 0, 0);
    };

    STAGE(0, 0);
    __syncthreads();
    int cur = 0;
    for (int kt = 32; kt < K; kt += 32) {
        STAGE(kt, cur ^ 1);
        COMPUTE(cur);
        __syncthreads();
        cur ^= 1;
    }
    COMPUTE(cur);
    __syncthreads();   // before LDS scratch reuse

    // ---- epilogue: LDS bounce -> coalesced 8/16B stores ----
    float* esc = (float*)smem + w * 1088;   // per-wave 16 rows x 68 words
#pragma unroll
    for (int i = 0; i < WI; ++i) {
#pragma unroll
        for (int j = 0; j < 4; ++j)
#pragma unroll
            for (int r = 0; r < 4; ++r)
                esc[(lq * 4 + r) * 68 + j * 16 + lc] = acc[i][j][r];
#pragma unroll
        for (int p = 0; p < 4; ++p) {
            int rr = p * 4 + lq;
            float4 v = *(const float4*)(esc + rr * 68 + lc * 4);
            int row = m0 + wr * (BM / 2) + i * 16 + rr;
            int col = n0 + wc * 64 + lc * 4;
            float4 bv = *(const float4*)(bias + col);
            v.x += bv.x; v.y += bv.y; v.z += bv.z; v.w += bv.w;
            size_t idx = (size_t)row * N + col;
            if (EPI == 0) {
                ushort4 o;
                o.x = f2bf(v.x); o.y = f2bf(v.y); o.z = f2bf(v.z); o.w = f2bf(v.w);
                *(ushort4*)((unsigned short*)outv + idx) = o;
            } else if (EPI == 1) {
                float g0 = 0.5f * v.x * (1.0f + erff(v.x * 0.70710678118f));
                float g1 = 0.5f * v.y * (1.0f + erff(v.y * 0.70710678118f));
                float g2 = 0.5f * v.z * (1.0f + erff(v.z * 0.70710678118f));
                float g3 = 0.5f * v.w * (1.0f + erff(v.w * 0.70710678118f));
                ushort4 o;
                o.x = f2bf(g0); o.y = f2bf(g1); o.z = f2bf(g2); o.w = f2bf(g3);
                *(ushort4*)((unsigned short*)outv + idx) = o;
            } else {
                float4 rv = *(const float4*)(res + idx);
                v.x += rv.x; v.y += rv.y; v.z += rv.z; v.w += rv.w;
                *(float4*)((float*)outv + idx) = v;
            }
        }
    }
}

// ---------------- fused flash attention (d=64, 64x64 tiles, 4 waves) ----------
__global__ __launch_bounds__(256) void k_attn(
        const unsigned short* __restrict__ Q, int ldq,
        const unsigned short* __restrict__ Kp, int ldk,
        const unsigned short* __restrict__ Vp, int ldv,
        unsigned short* __restrict__ O, int ldo,
        int T, int causal) {
    __shared__ unsigned short Ks[64 * 64];     // [t][d], chunk-swizzled
    __shared__ unsigned short Vt[64 * 64];     // [d][t], chunk-swizzled
    __shared__ unsigned short Ps[4][16 * 64];  // per-wave P, chunk-swizzled
    int nqt = T >> 6;
    int qt = blockIdx.x % nqt;
    int bh = blockIdx.x / nqt;
    int b = bh >> 4, h = bh & 15;
    int tid = threadIdx.x, w = tid >> 6, l = tid & 63;
    int lq = l >> 4, lc = l & 15;
    size_t qoff = (size_t)b * T * ldq + h * 64;
    size_t koff = (size_t)b * T * ldk + h * 64;
    size_t voff = (size_t)b * T * ldv + h * 64;
    s8v qf[2];
    {
        const unsigned short* qp = Q + qoff + (size_t)(qt * 64 + w * 16 + lc) * ldq + lq * 8;
        qf[0] = *(const s8v*)qp;
        qf[1] = *(const s8v*)(qp + 32);
    }
    f4v o_acc[4];
#pragma unroll
    for (int j = 0; j < 4; ++j) o_acc[j] = fzero();
    float mrow[4], lrow[4];
#pragma unroll
    for (int j = 0; j < 4; ++j) { mrow[j] = -3.0e38f; lrow[j] = 0.f; }
    int p = tid & 31, dbase = (tid >> 5) * 8;
    int ktend = causal ? (qt + 1) : (T >> 6);
    for (int kt = 0; kt < ktend; ++kt) {
#pragma unroll
        for (int s = 0; s < 2; ++s) {
            int idx = s * 256 + w * 64 + l;
            int t = idx >> 3;
            int ch = (idx & 7) ^ (t & 7);
            gload16(Kp + koff + (size_t)(kt * 64 + t) * ldk + ch * 8,
                    (char*)Ks + s * 4096 + w * 1024);
        }
        {
            const unsigned short* vp = Vp + voff + (size_t)(kt * 64 + 2 * p) * ldv + dbase;
            s8v v0 = *(const s8v*)vp;
            s8v v1 = *(const s8v*)(vp + ldv);
#pragma unroll
            for (int j = 0; j < 8; ++j) {
                int dd = dbase + j;
                unsigned int val = (unsigned short)v0[j] | ((unsigned)(unsigned short)v1[j] << 16);
                *(unsigned int*)((char*)Vt + dd * 128 +
                                 ((((p >> 2) ^ (dd & 7)) << 4) | ((p & 3) << 2))) = val;
            }
        }
        __syncthreads();
        f4v sa[4];
#pragma unroll
        for (int jn = 0; jn < 4; ++jn) {
            sa[jn] = fzero();
            int t = jn * 16 + lc;
#pragma unroll
            for (int kc = 0; kc < 2; ++kc) {
                s8v bf = *(const s8v*)((const char*)Ks + t * 128 +
                                       (((kc * 4 + lq) ^ (t & 7)) << 4));
                sa[jn] = __builtin_amdgcn_mfma_f32_16x16x32_bf16(qf[kc], bf, sa[jn], 0, 0, 0);
            }
        }
        bool diag = (causal && kt == qt);
#pragma unroll
        for (int j = 0; j < 4; ++j) {
            float pv[4];
            float tm = -3.0e38f;
#pragma unroll
            for (int jn = 0; jn < 4; ++jn) {
                float sv = sa[jn][j] * 0.125f;
                if (diag) {
                    int qg = w * 16 + lq * 4 + j;
                    int kg = jn * 16 + lc;
                    if (kg > qg) sv = -3.0e38f;
                }
                pv[jn] = sv;
                tm = fmaxf(tm, sv);
            }
#pragma unroll
            for (int m = 1; m < 16; m <<= 1) tm = fmaxf(tm, __shfl_xor(tm, m));
            float mnew = fmaxf(mrow[j], tm);
            float alpha = __expf(mrow[j] - mnew);
            mrow[j] = mnew;
            float rs = 0.f;
#pragma unroll
            for (int jn = 0; jn < 4; ++jn) {
                float e = __expf(pv[jn] - mnew);
                rs += e;
                int colx = jn * 16 + lc;
                int rowx = lq * 4 + j;
                *(unsigned short*)((char*)Ps[w] + rowx * 128 +
                                   ((((colx >> 3) ^ (rowx & 7)) << 4) | ((colx & 7) << 1))) = f2bf(e);
            }
#pragma unroll
            for (int m = 1; m < 16; m <<= 1) rs += __shfl_xor(rs, m);
            lrow[j] = lrow[j] * alpha + rs;
#pragma unroll
            for (int jn = 0; jn < 4; ++jn) o_acc[jn][j] *= alpha;
        }
#pragma unroll
        for (int kc = 0; kc < 2; ++kc) {
            s8v af = *(const s8v*)((const char*)Ps[w] + lc * 128 +
                                   (((kc * 4 + lq) ^ (lc & 7)) << 4));
#pragma unroll
            for (int jn = 0; jn < 4; ++jn) {
                int dd = jn * 16 + lc;
                s8v bf = *(const s8v*)((const char*)Vt + dd * 128 +
                                       (((kc * 4 + lq) ^ (dd & 7)) << 4));
                o_acc[jn] = __builtin_amdgcn_mfma_f32_16x16x32_bf16(af, bf, o_acc[jn], 0, 0, 0);
            }
        }
        __syncthreads();
    }
#pragma unroll
    for (int j = 0; j < 4; ++j) {
        float inv = 1.0f / lrow[j];
        int row = qt * 64 + w * 16 + lq * 4 + j;
#pragma unroll
        for (int jn = 0; jn < 4; ++jn)
            O[(size_t)(b * T + row) * ldo + h * 64 + jn * 16 + lc] = f2bf(o_acc[jn][j] * inv);
    }
}

// ---------------- orchestration ----------------
extern "C" void kernel_launch(void* const* d_in, const int* in_sizes, int n_in,
                              void* d_out, int out_size, void* d_ws, size_t ws_size,
                              hipStream_t stream) {
    const float* x     = (const float*)d_in[0];
    const float* ctx   = (const float*)d_in[1];
    const float* ln1_g = (const float*)d_in[2];
    const float* ln1_b = (const float*)d_in[3];
    const float* ln2_g = (const float*)d_in[4];
    const float* ln2_b = (const float*)d_in[5];
    const float* sa_wq = (const float*)d_in[6];  const float* sa_bq = (const float*)d_in[7];
    const float* sa_wk = (const float*)d_in[8];  const float* sa_bk = (const float*)d_in[9];
    const float* sa_wv = (const float*)d_in[10]; const float* sa_bv = (const float*)d_in[11];
    const float* sa_wo = (const float*)d_in[12]; const float* sa_bo = (const float*)d_in[13];
    const float* ca_wq = (const float*)d_in[14]; const float* ca_bq = (const float*)d_in[15];
    const float* ca_wk = (const float*)d_in[16]; const float* ca_bk = (const float*)d_in[17];
    const float* ca_wv = (const float*)d_in[18]; const float* ca_bv = (const float*)d_in[19];
    const float* ca_wo = (const float*)d_in[20]; const float* ca_bo = (const float*)d_in[21];
    const float* w1 = (const float*)d_in[22]; const float* b1 = (const float*)d_in[23];
    const float* w2 = (const float*)d_in[24]; const float* b2 = (const float*)d_in[25];
    float* out = (float*)d_out;

    char* ws = (char*)d_ws;
    const size_t MB = 1024 * 1024;
    unsigned short* wt_saq = (unsigned short*)(ws + 0 * MB);   // 2MB each; saq,sak,sav contiguous
    unsigned short* wt_sak = (unsigned short*)(ws + 2 * MB);
    unsigned short* wt_sav = (unsigned short*)(ws + 4 * MB);
    unsigned short* wt_sao = (unsigned short*)(ws + 6 * MB);
    unsigned short* wt_caq = (unsigned short*)(ws + 8 * MB);
    unsigned short* wt_cak = (unsigned short*)(ws + 10 * MB);  // cak,cav contiguous
    unsigned short* wt_cav = (unsigned short*)(ws + 12 * MB);
    unsigned short* wt_cao = (unsigned short*)(ws + 14 * MB);
    unsigned short* w1t    = (unsigned short*)(ws + 16 * MB);  // 8MB (4096,1024)
    unsigned short* w2t    = (unsigned short*)(ws + 24 * MB);  // 8MB (1024,4096)
    unsigned short* ctxb   = (unsigned short*)(ws + 32 * MB);  // 8MB; reused as h3 in MLP
    float*          x1     = (float*)        (ws + 40 * MB);   // 16MB
    unsigned short* qbuf   = (unsigned short*)(ws + 56 * MB);  // 8MB, start of qkv region
    unsigned short* kbuf   = (unsigned short*)(ws + 64 * MB);  // 8MB, kv region
    unsigned short* hln    = (unsigned short*)(ws + 80 * MB);  // 8MB (ln out / attn out)
    float*          bcat   = (float*)        (ws + 88 * MB);   // 20KB
    unsigned short* qkv = qbuf;   // (4096,3072) spans 56..80MB
    unsigned short* kv  = kbuf;   // (4096,2048) spans 64..80MB
    unsigned short* m1  = qbuf;   // (4096,4096) = 32MB spans 56..88MB
    unsigned short* h3  = ctxb;

    dim3 blk(256);
    // weight prep
    k_transpose_bf16<<<dim3(32, 32), blk, 0, stream>>>(sa_wq, wt_saq, 1024, 1024);
    k_transpose_bf16<<<dim3(32, 32), blk, 0, stream>>>(sa_wk, wt_sak, 1024, 1024);
    k_transpose_bf16<<<dim3(32, 32), blk, 0, stream>>>(sa_wv, wt_sav, 1024, 1024);
    k_transpose_bf16<<<dim3(32, 32), blk, 0, stream>>>(sa_wo, wt_sao, 1024, 1024);
    k_transpose_bf16<<<dim3(32, 32), blk, 0, stream>>>(ca_wq, wt_caq, 1024, 1024);
    k_transpose_bf16<<<dim3(32, 32), blk, 0, stream>>>(ca_wk, wt_cak, 1024, 1024);
    k_transpose_bf16<<<dim3(32, 32), blk, 0, stream>>>(ca_wv, wt_cav, 1024, 1024);
    k_transpose_bf16<<<dim3(32, 32), blk, 0, stream>>>(ca_wo, wt_cao, 1024, 1024);
    k_transpose_bf16<<<dim3(128, 32), blk, 0, stream>>>(w1, w1t, 1024, 4096);
    k_transpose_bf16<<<dim3(32, 128), blk, 0, stream>>>(w2, w2t, 4096, 1024);
    k_f32_to_bf16<<<dim3(2048), blk, 0, stream>>>(ctx, ctxb, 4 * 1024 * 1024);
    k_bias_cat<<<dim3(20), blk, 0, stream>>>(sa_bq, sa_bk, sa_bv, ca_bk, ca_bv, bcat);

    // ---- self attention: x1 = x + Wo(attn(ln1(x))) ----
    k_layernorm<<<dim3(4096), blk, 0, stream>>>(x, ln1_g, ln1_b, hln);
    k_gemm<0, 128><<<dim3(24 * 32), blk, 0, stream>>>(hln, wt_saq, bcat, nullptr, qkv, 4096, 3072, 1024);
    k_attn<<<dim3(1024), blk, 0, stream>>>(qkv, 3072, qkv + 1024, 3072, qkv + 2048, 3072,
                                           hln, 1024, 1024, 1);
    k_gemm<2, 64><<<dim3(64 * 8), blk, 0, stream>>>(hln, wt_sao, sa_bo, x, x1, 4096, 1024, 1024);

    // ---- cross attention: x2 = x1 + Wo(attn(ln2(x1), ctx)) ----
    k_layernorm<<<dim3(4096), blk, 0, stream>>>(x1, ln2_g, ln2_b, hln);
    k_gemm<0, 64><<<dim3(64 * 8), blk, 0, stream>>>(hln, wt_caq, ca_bq, nullptr, qbuf, 4096, 1024, 1024);
    k_gemm<0, 128><<<dim3(16 * 32), blk, 0, stream>>>(ctxb, wt_cak, bcat + 3072, nullptr, kv, 4096, 2048, 1024);
    k_attn<<<dim3(1024), blk, 0, stream>>>(qbuf, 1024, kv, 2048, kv + 1024, 2048,
                                           hln, 1024, 1024, 0);
    k_gemm<2, 64><<<dim3(64 * 8), blk, 0, stream>>>(hln, wt_cao, ca_bo, x1, out, 4096, 1024, 1024);

    // ---- MLP: out = x2 + W2(gelu(W1(ln2(x2)))) ----
    k_layernorm<<<dim3(4096), blk, 0, stream>>>(out, ln2_g, ln2_b, h3);
    k_gemm<1, 128><<<dim3(32 * 32), blk, 0, stream>>>(h3, w1t, b1, nullptr, m1, 4096, 4096, 1024);
    k_gemm<2, 64><<<dim3(64 * 8), blk, 0, stream>>>(m1, w2t, b2, out, out, 4096, 1024, 4096);
}